// Round 4
// baseline (433.568 us; speedup 1.0000x reference)
//
#include <hip/hip_runtime.h>
#include <math.h>

// Problem constants
#define BB 256          // batch
#define CC 256          // channels
#define MN 196          // H*W
#define TRI 32896       // C*(C+1)/2

// Split-f16 storage: u32 = {lo16: f16(hi), hi16: f16(32v - hi)} at x32 scale.
#define MSC 32.0f
#define INV_MSC  (1.0f/32.0f)
#define INV_MSC2 (1.0f/1024.0f)

typedef _Float16 f16;
typedef f16   f16x8 __attribute__((ext_vector_type(8)));
typedef float f32x4 __attribute__((ext_vector_type(4)));
typedef unsigned u32x4 __attribute__((ext_vector_type(4)));

__device__ __forceinline__ unsigned pack_split(float v) {
    f16 h = (f16)v;
    f16 l = (f16)(v - (float)h);
    return (unsigned)__builtin_bit_cast(unsigned short, h) |
           ((unsigned)__builtin_bit_cast(unsigned short, l) << 16);
}
__device__ __forceinline__ float unpack_split(unsigned w) {
    f16 h = __builtin_bit_cast(f16, (unsigned short)(w & 0xffffu));
    f16 l = __builtin_bit_cast(f16, (unsigned short)(w >> 16));
    return (float)h + (float)l;
}
__device__ __forceinline__ f16x8 swap_pairs(f16x8 v) {
    return __builtin_shufflevector(v, v, 1, 0, 3, 2, 5, 4, 7, 6);
}
__device__ __forceinline__ void gload_lds16(const unsigned* g, const f16* l) {
    __builtin_amdgcn_global_load_lds(
        (__attribute__((address_space(1))) void*)(size_t)g,
        (__attribute__((address_space(3))) void*)(unsigned)(size_t)l,
        16, 0, 0);
}

// ---------------------------------------------------------------------------
// Fused xsplit: per (b,c) row compute mean+var in-wave (butterfly), write
// split-f16 centered row (K padded 196 -> 224 with zeros) and vr.
// Kills the separate meanvar pass (one less full read of x).
// ---------------------------------------------------------------------------
__global__ __launch_bounds__(256) void xsplit_kernel(const float* __restrict__ x,
                                                     float* __restrict__ vr,
                                                     unsigned* __restrict__ xs, int b0) {
    int wave = (blockIdx.x * 256 + threadIdx.x) >> 6;   // bl*256 + c
    int lane = threadIdx.x & 63;
    int bl = wave >> 8;
    int c  = wave & 255;
    int bg = b0 + bl;
    const float* row = x + ((size_t)bg * CC + c) * MN;
    float a0 = row[lane], a1 = row[lane + 64], a2 = row[lane + 128];
    float a3 = (lane < MN - 192) ? row[lane + 192] : 0.0f;
    float s = a0 + a1 + a2 + a3;
    float q = a0 * a0 + a1 * a1 + a2 * a2 + a3 * a3;
    #pragma unroll
    for (int off = 32; off > 0; off >>= 1) {
        s += __shfl_xor(s, off, 64);
        q += __shfl_xor(q, off, 64);
    }
    float m = s * (1.0f / MN);
    if (lane == 0) vr[bg * CC + c] = q * (1.0f / MN) - m * m;
    unsigned* orow = xs + (size_t)bl * (CC * 224) + (size_t)c * 224;
    orow[lane]       = pack_split(MSC * (a0 - m));
    orow[lane + 64]  = pack_split(MSC * (a1 - m));
    orow[lane + 128] = pack_split(MSC * (a2 - m));
    if (lane < 4)       orow[lane + 192] = pack_split(MSC * (a3 - m));
    else if (lane < 32) orow[lane + 192] = 0u;
}

// normA[b] = sum_c vr[b,c] (per chunk)
__global__ __launch_bounds__(256) void norm_kernel(const float* __restrict__ vr,
                                                   float* __restrict__ inv,
                                                   float* __restrict__ snorm,
                                                   float* __restrict__ invs, int b0) {
    __shared__ float red[256];
    int b = b0 + blockIdx.x, i = threadIdx.x;
    red[i] = vr[b * CC + i];
    __syncthreads();
    for (int s = 128; s > 0; s >>= 1) {
        if (i < s) red[i] += red[i + s];
        __syncthreads();
    }
    if (i == 0) {
        float n = red[0];
        inv[b] = 1.0f / n;
        float sq = sqrtf(n);
        snorm[b] = sq;
        invs[b] = 1.0f / sq;
    }
}

// ---------------------------------------------------------------------------
// Split-f16 MFMA GEMM, memory-granularity-optimized.
// 128x128 tile, 512 thr (8 waves 2x4), wave 64x32, mfma_f32_16x16x32_f16 x2
// passes (bv / swap(bv)).
// K-chunk = 32 u32 = 128 B/row: staging is 128B-granular; global src is
// pre-XOR-swizzled (granule ^= row&7) and reads apply the same XOR ->
// conflict-free ds_read_b128 (rule 21: both-sides-or-neither).
// Epilogue: E-tile cooperatively loaded to LDS (512B/wave chunks), C main
// tile bounced through LDS and stored as 512B/wave chunks; mirror stays
// register-path u32x4. LDS = 64 KiB (staging and tile union) -> residency
// is LDS-capped at 2 blocks/CU; no launch-bounds hint needed.
// MODE 0: C = al*acc + be*E + diag (al,be opt * Sg[bg]), mirrored.
// MODE 1: out(triu) = acc * INV_MSC2 (fp32).
// MODE 2: COV, A=B=xs (LDK=224, 7 chunks), epilogue as MODE 0.
// ---------------------------------------------------------------------------
template <int MODE>
__global__ __launch_bounds__(512) void gemm512(const unsigned* __restrict__ Ag,
                                               const unsigned* __restrict__ Bg,
                                               const unsigned* __restrict__ Eg,
                                               void* __restrict__ Cg,
                                               const float alpha0, const float beta0,
                                               const float diag_add,
                                               const float* __restrict__ Sg, int b0) {
    constexpr int    LDK = (MODE == 2) ? 224 : 256;          // u32 per row
    constexpr int    KCH = LDK / 32;                         // 32-u32 chunks
    constexpr size_t BST = (size_t)CC * LDK;
    __shared__ __align__(16) unsigned char smem[65536];
    f16* AsBuf = (f16*)smem;                  // [2][8192] f16
    f16* BsBuf = (f16*)(smem + 32768);        // [2][8192] f16
    unsigned* tile = (unsigned*)smem;         // [128][128] u32 (epilogue)

    const int bl = blockIdx.x / 3;
    const int t  = blockIdx.x - 3 * bl;
    const int bg = b0 + bl;
    const int ti = (t == 2) ? 1 : 0;
    const int tj = (t == 0) ? 0 : 1;
    const int tid  = threadIdx.x;
    const int lane = tid & 63;
    const int wid  = tid >> 6;
    const int wrow = wid >> 2, wcol = wid & 3;

    const unsigned* Abase = Ag + (size_t)bl * BST + (size_t)(ti * 128) * LDK;
    const unsigned* Bbase = Bg + (size_t)bl * BST + (size_t)(tj * 128) * LDK;

    // staging: waves 0-3 -> A, 4-7 -> B; wave sw covers rows sw*32..+31.
    // LDS granule (row, G) holds logical granule G ^ (row&7); since rows per
    // load-inst advance by 8, the lane's XOR mask (lane>>3)&7 is constant.
    const int sw = wid & 3;
    const unsigned* gsrc = (wid < 4) ? Abase : Bbase;
    const unsigned* gsl = gsrc + (size_t)(sw * 32 + (lane >> 3)) * LDK
                               + (((lane & 7) ^ ((lane >> 3) & 7)) << 2);
    f16* mbase = (wid < 4) ? AsBuf : BsBuf;

    // frag read byte offsets (within one 16 KiB chunk buffer), per k-iter t
    int aoff[4][2], boff[2][2];
    #pragma unroll
    for (int ib = 0; ib < 4; ++ib) {
        int r = wrow * 64 + ib * 16 + (lane & 15);
        #pragma unroll
        for (int tt = 0; tt < 2; ++tt)
            aoff[ib][tt] = r * 128 + ((((tt * 4) + (lane >> 4)) ^ (r & 7)) << 4);
    }
    #pragma unroll
    for (int jb = 0; jb < 2; ++jb) {
        int r = wcol * 32 + jb * 16 + (lane & 15);
        #pragma unroll
        for (int tt = 0; tt < 2; ++tt)
            boff[jb][tt] = r * 128 + ((((tt * 4) + (lane >> 4)) ^ (r & 7)) << 4);
    }

    f32x4 acc[4][2];
    #pragma unroll
    for (int i = 0; i < 4; ++i)
        #pragma unroll
        for (int j = 0; j < 2; ++j) acc[i][j] = 0.0f;

    auto STAGE = [&](int nb, int ks) {
        const unsigned* s = gsl + (size_t)ks * 32;
        f16* d = mbase + nb * 8192 + sw * 2048;
        #pragma unroll
        for (int i = 0; i < 4; ++i)
            gload_lds16(s + (size_t)i * 8 * LDK, d + i * 512);
    };

    STAGE(0, 0);
    __syncthreads();
    #pragma unroll 1
    for (int ks = 0; ks < KCH; ++ks) {
        const int nb = ks & 1;
        if (ks + 1 < KCH) STAGE(nb ^ 1, ks + 1);
        const char* Ab8 = (const char*)(AsBuf + nb * 8192);
        const char* Bb8 = (const char*)(BsBuf + nb * 8192);
        #pragma unroll
        for (int tt = 0; tt < 2; ++tt) {
            f16x8 av[4], bv[2], bw[2];
            #pragma unroll
            for (int ib = 0; ib < 4; ++ib)
                av[ib] = *(const f16x8*)(Ab8 + aoff[ib][tt]);
            #pragma unroll
            for (int jb = 0; jb < 2; ++jb) {
                bv[jb] = *(const f16x8*)(Bb8 + boff[jb][tt]);
                bw[jb] = swap_pairs(bv[jb]);
            }
            #pragma unroll
            for (int ib = 0; ib < 4; ++ib)
                #pragma unroll
                for (int jb = 0; jb < 2; ++jb) {
                    acc[ib][jb] = __builtin_amdgcn_mfma_f32_16x16x32_f16(av[ib], bv[jb], acc[ib][jb], 0, 0, 0);
                    acc[ib][jb] = __builtin_amdgcn_mfma_f32_16x16x32_f16(av[ib], bw[jb], acc[ib][jb], 0, 0, 0);
                }
        }
        __syncthreads();   // staging landed (vmcnt drained) + chunk reads done
    }

    // C/D frag: col = lane&15, row = (lane>>4)*4 + q  (harness-verified)
    const int li0 = wrow * 64 + ((lane >> 4) << 2);     // local row base
    const int lj  = wcol * 32 + (lane & 15);            // local col
    const int gi0base = ti * 128 + li0;
    const int gjbase  = tj * 128 + lj;

    if (MODE != 1) {
        float sc = (Sg != nullptr) ? Sg[bg] : 1.0f;
        float al = alpha0 * sc;
        float be = beta0 * sc;
        unsigned* Cb = (unsigned*)Cg + (size_t)bl * CC * CC;
        const unsigned* Eb = (Eg != nullptr) ? Eg + (size_t)bl * CC * CC : nullptr;

        if (Eb) {   // cooperative 512B-chunk load of the E tile into LDS
            #pragma unroll
            for (int it = 0; it < 8; ++it) {
                int g = it * 512 + tid;
                int r = g >> 5, c4 = g & 31;
                *(u32x4*)&tile[r * 128 + c4 * 4] =
                    *(const u32x4*)&Eb[(size_t)(ti * 128 + r) * CC + tj * 128 + c4 * 4];
            }
            __syncthreads();
        }

        unsigned pk[4][2][4];
        #pragma unroll
        for (int ib = 0; ib < 4; ++ib)
            #pragma unroll
            for (int jb = 0; jb < 2; ++jb)
                #pragma unroll
                for (int q = 0; q < 4; ++q) {
                    int lr = li0 + q + 16 * ib;
                    int lc = lj + 16 * jb;
                    float val = al * acc[ib][jb][q];
                    if (Eb) val += be * unpack_split(tile[lr * 128 + lc]);
                    if (gi0base + q + 16 * ib == gjbase + 16 * jb) val += diag_add;
                    pk[ib][jb][q] = pack_split(val);
                }
        __syncthreads();   // all E reads done before deposit overwrites tile

        #pragma unroll
        for (int ib = 0; ib < 4; ++ib)
            #pragma unroll
            for (int jb = 0; jb < 2; ++jb)
                #pragma unroll
                for (int q = 0; q < 4; ++q)
                    tile[(li0 + q + 16 * ib) * 128 + lj + 16 * jb] = pk[ib][jb][q];
        __syncthreads();

        // cooperative 512B-chunk store of the main tile
        #pragma unroll
        for (int it = 0; it < 8; ++it) {
            int g = it * 512 + tid;
            int r = g >> 5, c4 = g & 31;
            *(u32x4*)&Cb[(size_t)(ti * 128 + r) * CC + tj * 128 + c4 * 4] =
                *(const u32x4*)&tile[r * 128 + c4 * 4];
        }
        if (ti != tj) {   // mirror (register path, 64B chunks) -> exact symmetry
            #pragma unroll
            for (int ib = 0; ib < 4; ++ib)
                #pragma unroll
                for (int jb = 0; jb < 2; ++jb) {
                    int gj  = gjbase + 16 * jb;
                    int gi0 = gi0base + 16 * ib;
                    u32x4 m = {pk[ib][jb][0], pk[ib][jb][1], pk[ib][jb][2], pk[ib][jb][3]};
                    *(u32x4*)&Cb[(size_t)gj * CC + gi0] = m;
                }
        }
    } else {
        float* ob = (float*)Cg + (size_t)bg * TRI;
        #pragma unroll
        for (int ib = 0; ib < 4; ++ib)
            #pragma unroll
            for (int jb = 0; jb < 2; ++jb) {
                int gi0 = gi0base + ib * 16;
                int gj  = gjbase + jb * 16;
                #pragma unroll
                for (int q = 0; q < 4; ++q) {
                    int gi = gi0 + q;
                    if (gj >= gi)
                        ob[gi * CC - (gi * (gi - 1)) / 2 - gi + gj] = acc[ib][jb][q] * INV_MSC2;
                }
            }
    }
}

// ---------------------------------------------------------------------------
// Per chunk of g batches (4 slots of 256KB/batch):
//   xs  = split(MSC*(x-mu)) fused mean/var     -> s1
//   A   = Gram(xs)*inv/(MSC*MN)  (MODE 2)      -> s0
//   Y1  = -0.5 A@A + 1.5 A                     -> s1
//   ZY1 = 0.25 A@Y1 - 0.75 Y1 + 1.5 I          -> s2
//   Y2' = sqrt(n)*(Y1@ZY1)                     -> s3
//   Z2' = (1/sqrt(n))*(-0.5 ZY1@A + 1.5 ZY1)   -> s1
//   T   = -0.5 Z2'@Y2' + 1.5 I                 -> s0
//   out = triu(Y2'@T)/MSC^2                    -> d_out
// Scalar scratch in the tail of d_out (only the last FINAL writes there).
// ---------------------------------------------------------------------------
extern "C" void kernel_launch(void* const* d_in, const int* in_sizes, int n_in,
                              void* d_out, int out_size, void* d_ws, size_t ws_size,
                              hipStream_t stream) {
    const float* x = (const float*)d_in[0];
    float* out = (float*)d_out;
    unsigned* ws = (unsigned*)d_ws;

    const int SCR = BB * CC + 3 * BB;           // vr, inv, snorm, invs
    float* vr    = out + (out_size - SCR);
    float* inv   = vr + BB * CC;
    float* snorm = inv + BB;
    float* invs  = snorm + BB;

    size_t per_b = 4ull * CC * CC * sizeof(unsigned);   // 1 MiB per batch
    int gmax = (int)(ws_size / per_b);
    int g = 1;
    while (g * 2 <= gmax && g * 2 <= BB) g *= 2;

    size_t slotf = (size_t)g * CC * CC;
    unsigned* s0 = ws;
    unsigned* s1 = ws + slotf;
    unsigned* s2 = ws + 2 * slotf;
    unsigned* s3 = ws + 3 * slotf;

    for (int b0 = 0; b0 < BB; b0 += g) {
        xsplit_kernel<<<g * 64, 256, 0, stream>>>(x, vr, s1, b0);
        norm_kernel<<<g, 256, 0, stream>>>(vr, inv, snorm, invs, b0);
        // A = Gram(xs) * inv / (MSC*MN)   (stored MSC-scaled)
        gemm512<2><<<g * 3, 512, 0, stream>>>(s1, s1, nullptr, (void*)s0,
                                              1.0f / (MSC * MN), 0.0f, 0.0f, inv, b0);
        // Y1 = -0.5*(A@A) + 1.5*A
        gemm512<0><<<g * 3, 512, 0, stream>>>(s0, s0, s0, (void*)s1, -0.5f * INV_MSC, 1.5f, 0.0f, nullptr, b0);
        // ZY1 = 0.25*(A@Y1) - 0.75*Y1 + 1.5*I
        gemm512<0><<<g * 3, 512, 0, stream>>>(s0, s1, s1, (void*)s2, 0.25f * INV_MSC, -0.75f, 1.5f * MSC, nullptr, b0);
        // Y2' = snorm*(Y1@ZY1)
        gemm512<0><<<g * 3, 512, 0, stream>>>(s1, s2, nullptr, (void*)s3, INV_MSC, 0.0f, 0.0f, snorm, b0);
        // Z2' = invs*(-0.5*(ZY1@A) + 1.5*ZY1)
        gemm512<0><<<g * 3, 512, 0, stream>>>(s2, s0, s2, (void*)s1, -0.5f * INV_MSC, 1.5f, 0.0f, invs, b0);
        // T = -0.5*(Z2'@Y2') + 1.5*I
        gemm512<0><<<g * 3, 512, 0, stream>>>(s1, s3, nullptr, (void*)s0, -0.5f * INV_MSC, 0.0f, 1.5f * MSC, nullptr, b0);
        // out = triu(Y2'@T) / MSC^2
        gemm512<1><<<g * 3, 512, 0, stream>>>(s3, s0, nullptr, d_out, 0.0f, 0.0f, 0.0f, nullptr, b0);
    }
}

// Round 5
// 400.137 us; speedup vs baseline: 1.0835x; 1.0835x over previous
//
#include <hip/hip_runtime.h>
#include <math.h>

// Problem constants
#define BB 256          // batch
#define CC 256          // channels
#define MN 196          // H*W
#define TRI 32896       // C*(C+1)/2

// Split-f16 storage: u32 = {lo16: f16(hi), hi16: f16(32v - hi)} at x32 scale.
#define MSC 32.0f
#define INV_MSC  (1.0f/32.0f)
#define INV_MSC2 (1.0f/1024.0f)

typedef _Float16 f16;
typedef f16   f16x8 __attribute__((ext_vector_type(8)));
typedef float f32x4 __attribute__((ext_vector_type(4)));
typedef unsigned u32x4 __attribute__((ext_vector_type(4)));

__device__ __forceinline__ unsigned pack_split(float v) {
    f16 h = (f16)v;
    f16 l = (f16)(v - (float)h);
    return (unsigned)__builtin_bit_cast(unsigned short, h) |
           ((unsigned)__builtin_bit_cast(unsigned short, l) << 16);
}
__device__ __forceinline__ float unpack_split(unsigned w) {
    f16 h = __builtin_bit_cast(f16, (unsigned short)(w & 0xffffu));
    f16 l = __builtin_bit_cast(f16, (unsigned short)(w >> 16));
    return (float)h + (float)l;
}
__device__ __forceinline__ f16x8 swap_pairs(f16x8 v) {
    return __builtin_shufflevector(v, v, 1, 0, 3, 2, 5, 4, 7, 6);
}
__device__ __forceinline__ void gload_lds16(const unsigned* g, const f16* l) {
    __builtin_amdgcn_global_load_lds(
        (__attribute__((address_space(1))) void*)(size_t)g,
        (__attribute__((address_space(3))) void*)(unsigned)(size_t)l,
        16, 0, 0);
}

// ---------------------------------------------------------------------------
// Fused xsplit: per (b,c) row compute mean+var in-wave, write split-f16
// centered row padded K 196 -> 256 with zeros (so cov is a plain 256-K GEMM).
// xs[batch] is exactly 256x256 u32 = one slot.
// ---------------------------------------------------------------------------
__global__ __launch_bounds__(256) void xsplit_kernel(const float* __restrict__ x,
                                                     float* __restrict__ vr,
                                                     unsigned* __restrict__ xs, int b0) {
    int wave = (blockIdx.x * 256 + threadIdx.x) >> 6;   // bl*256 + c
    int lane = threadIdx.x & 63;
    int bl = wave >> 8;
    int c  = wave & 255;
    int bg = b0 + bl;
    const float* row = x + ((size_t)bg * CC + c) * MN;
    float a0 = row[lane], a1 = row[lane + 64], a2 = row[lane + 128];
    float a3 = (lane < MN - 192) ? row[lane + 192] : 0.0f;
    float s = a0 + a1 + a2 + a3;
    float q = a0 * a0 + a1 * a1 + a2 * a2 + a3 * a3;
    #pragma unroll
    for (int off = 32; off > 0; off >>= 1) {
        s += __shfl_xor(s, off, 64);
        q += __shfl_xor(q, off, 64);
    }
    float m = s * (1.0f / MN);
    if (lane == 0) vr[bg * CC + c] = q * (1.0f / MN) - m * m;
    unsigned* orow = xs + ((size_t)bl * CC + c) * 256;
    orow[lane]       = pack_split(MSC * (a0 - m));
    orow[lane + 64]  = pack_split(MSC * (a1 - m));
    orow[lane + 128] = pack_split(MSC * (a2 - m));
    orow[lane + 192] = (lane < 4) ? pack_split(MSC * (a3 - m)) : 0u;
}

// normA[b] = sum_c vr[b,c] (per chunk)
__global__ __launch_bounds__(256) void norm_kernel(const float* __restrict__ vr,
                                                   float* __restrict__ inv,
                                                   float* __restrict__ snorm,
                                                   float* __restrict__ invs, int b0) {
    __shared__ float red[256];
    int b = b0 + blockIdx.x, i = threadIdx.x;
    red[i] = vr[b * CC + i];
    __syncthreads();
    for (int s = 128; s > 0; s >>= 1) {
        if (i < s) red[i] += red[i + s];
        __syncthreads();
    }
    if (i == 0) {
        float n = red[0];
        inv[b] = 1.0f / n;
        float sq = sqrtf(n);
        snorm[b] = sq;
        invs[b] = 1.0f / sq;
    }
}

// ---------------------------------------------------------------------------
// Split-f16 MFMA GEMM, latency-optimized geometry.
// 128x128 tile, 256 threads = 4 waves (2x2), wave tile 64x64 (4x4 frags of
// 16x16, 16 independent acc chains -> MFMA ILP within one wave).
// ALL FOUR tiles per matrix (grid = g*4, no mirror writes); all operand
// matrices are symmetric (polynomials of A / Gram), rows read as columns.
// K-chunk = 32 u32 (128B/row); staging via global_load_lds w=16, both-sides
// XOR granule swizzle (granule ^= row&7) -> even b128 bank-quad spread.
// XCD-chunked blockIdx swizzle (grid divisible by 8) for L2 panel reuse.
// Epilogue: E and C bounced through LDS (1KB/inst coalesced global ops).
// FINAL: triu(acc)*INV_MSC2 -> f32 out; t10 blocks exit early.
// ---------------------------------------------------------------------------
template <bool FINAL>
__global__ __launch_bounds__(256) void gemm256(const unsigned* __restrict__ Ag,
                                               const unsigned* __restrict__ Bg,
                                               const unsigned* __restrict__ Eg,
                                               void* __restrict__ Cg,
                                               const float alpha0, const float beta0,
                                               const float diag_add,
                                               const float* __restrict__ Sg, int b0) {
    __shared__ __align__(16) unsigned char smem[65536];
    // staging: A [2][128 rows][128B] at 0..32768 ; B at 32768..65536
    // epilogue union: tile[128][128] u32 (full 64KB), used after final barrier

    int bid = blockIdx.x;
    const int nwg = gridDim.x;
    if ((nwg & 7) == 0) {                   // bijective XCD-chunked swizzle
        const int cpx = nwg >> 3;
        bid = (bid & 7) * cpx + (bid >> 3);
    }
    const int bl = bid >> 2;
    const int t  = bid & 3;
    const int ti = t >> 1, tj = t & 1;
    if (FINAL && ti == 1 && tj == 0) return;   // strictly-lower tile unused
    const int bg = b0 + bl;
    const int tid  = threadIdx.x;
    const int lane = tid & 63;
    const int wid  = tid >> 6;              // 0..3
    const int wr = wid >> 1, wc = wid & 1;
    const int h = lane >> 4;                // 0..3
    const int d = lane & 15;                // frag col / dest granule base

    const unsigned* Abase = Ag + (size_t)bl * (CC * CC) + (size_t)(ti * 128) * 256;
    const unsigned* Bbase = Bg + (size_t)bl * (CC * CC) + (size_t)(tj * 128) * 256;

    // staging roles: waves 0-1 -> A rows (wid&1)*64..+63, waves 2-3 -> B.
    const unsigned* gpan = (wid < 2) ? Abase : Bbase;
    f16* lpan = (f16*)(smem + ((wid < 2) ? 0 : 32768));
    const int rbase = (wid & 1) * 64;
    const int sr = lane >> 3;               // row-within-inst 0..7
    const int sg = (lane & 7) ^ (lane >> 3);// source granule (involution, row&7=sr)

    auto STAGE = [&](int nb, int ks) {
        #pragma unroll
        for (int i = 0; i < 8; ++i) {
            const unsigned* src = gpan + (size_t)(rbase + i * 8 + sr) * 256
                                       + ks * 32 + sg * 4;
            f16* dst = lpan + nb * 8192 + (rbase + i * 8) * 64;  // +lane*16B by HW
            gload_lds16(src, dst);
        }
    };

    f32x4 acc[4][4];
    #pragma unroll
    for (int i = 0; i < 4; ++i)
        #pragma unroll
        for (int j = 0; j < 4; ++j) acc[i][j] = 0.0f;

    STAGE(0, 0);
    __syncthreads();
    #pragma unroll 1
    for (int ks = 0; ks < 8; ++ks) {
        const int nb = ks & 1;
        if (ks < 7) STAGE(nb ^ 1, ks + 1);
        #pragma unroll
        for (int kk = 0; kk < 2; ++kk) {
            // frag rows: ra = wr*64+ib*16+d (ra&7 = d&7); granule (kk*4+h)^(d&7)
            const int swz = (((kk * 4 + h) ^ (d & 7)) << 4);
            f16x8 av[4], bv[4], bw[4];
            #pragma unroll
            for (int ib = 0; ib < 4; ++ib)
                av[ib] = *(const f16x8*)(smem + nb * 16384
                            + (wr * 64 + ib * 16 + d) * 128 + swz);
            #pragma unroll
            for (int jb = 0; jb < 4; ++jb) {
                bv[jb] = *(const f16x8*)(smem + 32768 + nb * 16384
                            + (wc * 64 + jb * 16 + d) * 128 + swz);
                bw[jb] = swap_pairs(bv[jb]);
            }
            #pragma unroll
            for (int ib = 0; ib < 4; ++ib)
                #pragma unroll
                for (int jb = 0; jb < 4; ++jb) {
                    acc[ib][jb] = __builtin_amdgcn_mfma_f32_16x16x32_f16(av[ib], bv[jb], acc[ib][jb], 0, 0, 0);
                    acc[ib][jb] = __builtin_amdgcn_mfma_f32_16x16x32_f16(av[ib], bw[jb], acc[ib][jb], 0, 0, 0);
                }
        }
        __syncthreads();   // staged chunk landed (vmcnt drained) + reads done
    }

    // C/D frag: col = lane&15 (=d), row = h*4 + q  (harness-verified)
    const int li0 = wr * 64 + h * 4;        // local row base (+ib*16+q)
    const int lj0 = wc * 64 + d;            // local col (+jb*16)
    const int gi0 = ti * 128 + li0;
    const int gj0 = tj * 128 + lj0;
    unsigned* tile = (unsigned*)smem;       // 128x128 u32 epilogue buffer

    if (!FINAL) {
        const float sc = (Sg != nullptr) ? Sg[bg] : 1.0f;
        const float al = alpha0 * sc;
        const float be = beta0 * sc;
        unsigned* Cb = (unsigned*)Cg + (size_t)bl * CC * CC;
        const unsigned* Eb = (Eg != nullptr) ? Eg + (size_t)bl * CC * CC : nullptr;

        if (Eb) {   // coalesced 1KB/inst load of E tile into LDS
            #pragma unroll
            for (int it = 0; it < 16; ++it) {
                int f = it * 256 + tid;
                int r = f >> 5, c4 = f & 31;
                *(u32x4*)&tile[r * 128 + c4 * 4] =
                    *(const u32x4*)&Eb[(size_t)(ti * 128 + r) * CC + tj * 128 + c4 * 4];
            }
            __syncthreads();
        }

        unsigned pk[4][4][4];
        #pragma unroll
        for (int ib = 0; ib < 4; ++ib)
            #pragma unroll
            for (int jb = 0; jb < 4; ++jb)
                #pragma unroll
                for (int q = 0; q < 4; ++q) {
                    int lr = li0 + ib * 16 + q;
                    int lc = lj0 + jb * 16;
                    float val = al * acc[ib][jb][q];
                    if (Eb) val += be * unpack_split(tile[lr * 128 + lc]);
                    if (gi0 + ib * 16 + q == gj0 + jb * 16) val += diag_add;
                    pk[ib][jb][q] = pack_split(val);
                }
        __syncthreads();   // E reads done before deposit overwrites tile

        #pragma unroll
        for (int ib = 0; ib < 4; ++ib)
            #pragma unroll
            for (int jb = 0; jb < 4; ++jb)
                #pragma unroll
                for (int q = 0; q < 4; ++q)
                    tile[(li0 + ib * 16 + q) * 128 + lj0 + jb * 16] = pk[ib][jb][q];
        __syncthreads();

        #pragma unroll
        for (int it = 0; it < 16; ++it) {   // coalesced 1KB/inst store
            int f = it * 256 + tid;
            int r = f >> 5, c4 = f & 31;
            *(u32x4*)&Cb[(size_t)(ti * 128 + r) * CC + tj * 128 + c4 * 4] =
                *(const u32x4*)&tile[r * 128 + c4 * 4];
        }
    } else {
        float* ob = (float*)Cg + (size_t)bg * TRI;
        #pragma unroll
        for (int ib = 0; ib < 4; ++ib)
            #pragma unroll
            for (int jb = 0; jb < 4; ++jb) {
                int gib = gi0 + ib * 16;
                int gj  = gj0 + jb * 16;
                #pragma unroll
                for (int q = 0; q < 4; ++q) {
                    int gi = gib + q;
                    if (gj >= gi)
                        ob[gi * CC - (gi * (gi - 1)) / 2 - gi + gj] = acc[ib][jb][q] * INV_MSC2;
                }
            }
    }
}

// ---------------------------------------------------------------------------
// Per chunk of g batches (4 slots of 256KB/batch):
//   xs  = split(MSC*(x-mu)), K padded to 256   -> s1
//   A   = Gram(xs)*inv/(MSC*MN)                -> s0   (plain gemm, Sg=inv)
//   Y1  = -0.5 A@A + 1.5 A                     -> s1
//   ZY1 = 0.25 A@Y1 - 0.75 Y1 + 1.5 I          -> s2
//   Y2' = sqrt(n)*(Y1@ZY1)                     -> s3
//   Z2' = (1/sqrt(n))*(-0.5 ZY1@A + 1.5 ZY1)   -> s1
//   T   = -0.5 Z2'@Y2' + 1.5 I                 -> s0
//   out = triu(Y2'@T)/MSC^2                    -> d_out
// Scalar scratch in the tail of d_out (only the last FINAL writes there).
// ---------------------------------------------------------------------------
extern "C" void kernel_launch(void* const* d_in, const int* in_sizes, int n_in,
                              void* d_out, int out_size, void* d_ws, size_t ws_size,
                              hipStream_t stream) {
    const float* x = (const float*)d_in[0];
    float* out = (float*)d_out;
    unsigned* ws = (unsigned*)d_ws;

    const int SCR = BB * CC + 3 * BB;           // vr, inv, snorm, invs
    float* vr    = out + (out_size - SCR);
    float* inv   = vr + BB * CC;
    float* snorm = inv + BB;
    float* invs  = snorm + BB;

    size_t per_b = 4ull * CC * CC * sizeof(unsigned);   // 1 MiB per batch
    int gmax = (int)(ws_size / per_b);
    int g = 1;
    while (g * 2 <= gmax && g * 2 <= BB) g *= 2;

    size_t slotf = (size_t)g * CC * CC;
    unsigned* s0 = ws;
    unsigned* s1 = ws + slotf;
    unsigned* s2 = ws + 2 * slotf;
    unsigned* s3 = ws + 3 * slotf;

    for (int b0 = 0; b0 < BB; b0 += g) {
        xsplit_kernel<<<g * 64, 256, 0, stream>>>(x, vr, s1, b0);
        norm_kernel<<<g, 256, 0, stream>>>(vr, inv, snorm, invs, b0);
        // A = Gram(xs) * inv / (MSC*MN)   (stored MSC-scaled)
        gemm256<false><<<g * 4, 256, 0, stream>>>(s1, s1, nullptr, (void*)s0,
                                                  1.0f / (MSC * MN), 0.0f, 0.0f, inv, b0);
        // Y1 = -0.5*(A@A) + 1.5*A
        gemm256<false><<<g * 4, 256, 0, stream>>>(s0, s0, s0, (void*)s1, -0.5f * INV_MSC, 1.5f, 0.0f, nullptr, b0);
        // ZY1 = 0.25*(A@Y1) - 0.75*Y1 + 1.5*I
        gemm256<false><<<g * 4, 256, 0, stream>>>(s0, s1, s1, (void*)s2, 0.25f * INV_MSC, -0.75f, 1.5f * MSC, nullptr, b0);
        // Y2' = snorm*(Y1@ZY1)
        gemm256<false><<<g * 4, 256, 0, stream>>>(s1, s2, nullptr, (void*)s3, INV_MSC, 0.0f, 0.0f, snorm, b0);
        // Z2' = invs*(-0.5*(ZY1@A) + 1.5*ZY1)
        gemm256<false><<<g * 4, 256, 0, stream>>>(s2, s0, s2, (void*)s1, -0.5f * INV_MSC, 1.5f, 0.0f, invs, b0);
        // T = -0.5*(Z2'@Y2') + 1.5*I
        gemm256<false><<<g * 4, 256, 0, stream>>>(s1, s3, nullptr, (void*)s0, -0.5f * INV_MSC, 0.0f, 1.5f * MSC, nullptr, b0);
        // out = triu(Y2'@T) / MSC^2
        gemm256<true><<<g * 4, 256, 0, stream>>>(s3, s0, nullptr, d_out, 0.0f, 0.0f, 0.0f, nullptr, b0);
    }
}